// Round 1
// baseline (2586.865 us; speedup 1.0000x reference)
//
#include <hip/hip_runtime.h>
#include <math.h>

// Problem constants (from reference)
#define B  2
#define S  2048
#define DM 1024
#define H  16
#define Dh 64
#define BH (B*H)

// ---------------------------------------------------------------------------
// Kernel 1: projection GEMM.  C = X @ W^T
//   X: (B*S, DM) fp32 row-major, W: (DM, DM) fp32 row-major (rows = out dim)
//   out: [B, H, S, Dh] fp32
// Tile: BM=64 x BN=64 x BK=16, 256 threads, 4x4 microtile per thread.
// ---------------------------------------------------------------------------
#define BM 64
#define BN 64
#define BK 16

__global__ __launch_bounds__(256) void proj_kernel(const float* __restrict__ X,
                                                   const float* __restrict__ W,
                                                   float* __restrict__ out) {
    __shared__ __align__(16) float As[BK][BM];
    __shared__ __align__(16) float Bs[BK][BN];

    const int t  = threadIdx.x;
    const int tx = t & 15;        // n direction
    const int ty = t >> 4;        // m direction
    const int m0 = blockIdx.x * BM;
    const int n0 = blockIdx.y * BN;

    const int arow = t >> 2;            // 0..63
    const int acol = (t & 3) * 4;       // 0,4,8,12

    float acc[4][4] = {};

    for (int k0 = 0; k0 < DM; k0 += BK) {
        // global loads (coalesced 16B per lane)
        const float4 a = *(const float4*)(X + (size_t)(m0 + arow) * DM + k0 + acol);
        const float4 w = *(const float4*)(W + (size_t)(n0 + arow) * DM + k0 + acol);
        __syncthreads();
        As[acol + 0][arow] = a.x; As[acol + 1][arow] = a.y;
        As[acol + 2][arow] = a.z; As[acol + 3][arow] = a.w;
        Bs[acol + 0][arow] = w.x; Bs[acol + 1][arow] = w.y;
        Bs[acol + 2][arow] = w.z; Bs[acol + 3][arow] = w.w;
        __syncthreads();

        #pragma unroll
        for (int kk = 0; kk < BK; ++kk) {
            const float4 a4 = *(const float4*)&As[kk][ty * 4];
            const float4 b4 = *(const float4*)&Bs[kk][tx * 4];
            const float av[4] = {a4.x, a4.y, a4.z, a4.w};
            const float bv[4] = {b4.x, b4.y, b4.z, b4.w};
            #pragma unroll
            for (int i = 0; i < 4; ++i)
                #pragma unroll
                for (int j = 0; j < 4; ++j)
                    acc[i][j] += av[i] * bv[j];
        }
    }

    // epilogue: out[b, h, s, d]; n-tile is exactly one head (BN == Dh)
    const int hh = n0 >> 6;
    #pragma unroll
    for (int i = 0; i < 4; ++i) {
        const int m  = m0 + ty * 4 + i;
        const int bb = m >> 11;          // m / S
        const int ss = m & (S - 1);
        const float4 ov = make_float4(acc[i][0], acc[i][1], acc[i][2], acc[i][3]);
        *(float4*)(out + ((size_t)(bb * H + hh) * S + ss) * Dh + tx * 4) = ov;
    }
}

// ---------------------------------------------------------------------------
// Kernel 2: RoPE (+ q scale 1/sqrt(D)), in-place on Q and K. One thread per
// (b,h,s,i) rotation pair, i in [0,32).
// ---------------------------------------------------------------------------
__global__ __launch_bounds__(256) void rope_kernel(float* __restrict__ Q,
                                                   float* __restrict__ K,
                                                   const int* __restrict__ pos) {
    const int idx = blockIdx.x * 256 + threadIdx.x;   // < B*H*S*32 = 2^21
    const int i = idx & 31;
    const int s = (idx >> 5) & (S - 1);
    const int h = (idx >> 16) & (H - 1);
    const int b = idx >> 20;

    const float p   = (float)pos[b * S + s];
    // inv_freq = 10000^{-(2i)/64}, fp32 like the reference
    const float inv = powf(10000.0f, -(float)(2 * i) * (1.0f / 64.0f));
    const float ang = p * inv;
    float sn, cs;
    sincosf(ang, &sn, &cs);

    const size_t base = ((size_t)(b * H + h) * S + s) * Dh;
    const float q0 = Q[base + i], q1 = Q[base + i + 32];
    Q[base + i]      = (q0 * cs - q1 * sn) * 0.125f;   // D^-0.5 = 0.125
    Q[base + i + 32] = (q1 * cs + q0 * sn) * 0.125f;
    const float k0 = K[base + i], k1 = K[base + i + 32];
    K[base + i]      = (k0 * cs - k1 * sn);
    K[base + i + 32] = (k1 * cs + k0 * sn);
}

// ---------------------------------------------------------------------------
// Kernel 3: flash-style attention, fp32.
//   grid = (S/256, B*H), block = 256. One q-row per thread.
//   K/V tiles (64 keys x 64) staged in LDS; compute reads are wave-uniform
//   broadcasts (conflict-free). Online softmax with 16-key subtiles.
// ---------------------------------------------------------------------------
__global__ __launch_bounds__(256) void attn_kernel(const float* __restrict__ Q,
                                                   const float* __restrict__ K,
                                                   const float* __restrict__ V,
                                                   const float* __restrict__ mask,
                                                   float* __restrict__ out) {
    __shared__ __align__(16) float Ks[64 * 64];
    __shared__ __align__(16) float Vs[64 * 64];

    const int tid = threadIdx.x;
    const int bh  = blockIdx.y;
    const int b   = bh >> 4;         // / H
    const int h   = bh & 15;
    const int r   = blockIdx.x * 256 + tid;   // q row within (b,h)

    float4 q[16], o[16];
    const float* qp = Q + ((size_t)bh * S + r) * Dh;
    #pragma unroll
    for (int c = 0; c < 16; ++c) {
        q[c] = ((const float4*)qp)[c];
        o[c] = make_float4(0.f, 0.f, 0.f, 0.f);
    }
    float mi = -INFINITY, li = 0.f;
    const float* mrow = mask + ((size_t)b * S + r) * S;   // mask[b,0,r,:]

    for (int kt = 0; kt < S / 64; ++kt) {
        __syncthreads();
        #pragma unroll
        for (int c = 0; c < 4; ++c) {
            const int chunk = tid + c * 256;          // 0..1023
            const int row   = chunk >> 4;             // 0..63
            const int col   = (chunk & 15) << 2;      // 0..60
            const size_t g  = ((size_t)bh * S + kt * 64 + row) * Dh + col;
            *(float4*)&Ks[row * 64 + col] = *(const float4*)(K + g);
            *(float4*)&Vs[row * 64 + col] = *(const float4*)(V + g);
        }
        __syncthreads();

        #pragma unroll
        for (int jt = 0; jt < 4; ++jt) {
            float sc[16];
            #pragma unroll
            for (int jj = 0; jj < 16; ++jj) {
                const float* kp = &Ks[(jt * 16 + jj) * 64];
                float s0 = 0.f, s1 = 0.f, s2 = 0.f, s3 = 0.f;
                #pragma unroll
                for (int c = 0; c < 16; ++c) {
                    const float4 kv = ((const float4*)kp)[c];
                    s0 += q[c].x * kv.x; s1 += q[c].y * kv.y;
                    s2 += q[c].z * kv.z; s3 += q[c].w * kv.w;
                }
                sc[jj] = (s0 + s1) + (s2 + s3);
            }
            // + attention mask (contiguous per-row slice)
            #pragma unroll
            for (int g = 0; g < 4; ++g) {
                const float4 mv = *(const float4*)(mrow + kt * 64 + jt * 16 + g * 4);
                sc[g * 4 + 0] += mv.x; sc[g * 4 + 1] += mv.y;
                sc[g * 4 + 2] += mv.z; sc[g * 4 + 3] += mv.w;
            }

            float tmax = sc[0];
            #pragma unroll
            for (int jj = 1; jj < 16; ++jj) tmax = fmaxf(tmax, sc[jj]);
            const float mnew = fmaxf(mi, tmax);
            const float corr = __expf(mi - mnew);     // exp(-inf)=0 on first tile
            li *= corr;
            #pragma unroll
            for (int c = 0; c < 16; ++c) {
                o[c].x *= corr; o[c].y *= corr; o[c].z *= corr; o[c].w *= corr;
            }
            #pragma unroll
            for (int jj = 0; jj < 16; ++jj) {
                const float p = __expf(sc[jj] - mnew);
                li += p;
                const float* vp = &Vs[(jt * 16 + jj) * 64];
                #pragma unroll
                for (int c = 0; c < 16; ++c) {
                    const float4 vv = ((const float4*)vp)[c];
                    o[c].x += p * vv.x; o[c].y += p * vv.y;
                    o[c].z += p * vv.z; o[c].w += p * vv.w;
                }
            }
            mi = mnew;
        }
    }

    const float inv = 1.f / li;
    float* op = out + ((size_t)b * S + r) * DM + h * Dh;   // ctx transpose fused
    #pragma unroll
    for (int c = 0; c < 16; ++c) {
        float4 ov = o[c];
        ov.x *= inv; ov.y *= inv; ov.z *= inv; ov.w *= inv;
        ((float4*)op)[c] = ov;
    }
}

// ---------------------------------------------------------------------------
extern "C" void kernel_launch(void* const* d_in, const int* in_sizes, int n_in,
                              void* d_out, int out_size, void* d_ws, size_t ws_size,
                              hipStream_t stream) {
    const float* hs   = (const float*)d_in[0];  // (B,S,DM)
    const float* mask = (const float*)d_in[1];  // (B,1,S,S)
    const int*   pos  = (const int*)  d_in[2];  // (B,S)
    const float* Wq   = (const float*)d_in[3];
    const float* Wk   = (const float*)d_in[4];
    const float* Wv   = (const float*)d_in[5];
    float* out = (float*)d_out;

    // workspace: Q, K, V each B*H*S*Dh fp32 (16.78 MB each, 50.3 MB total)
    const size_t qkv_elems = (size_t)B * H * S * Dh;
    float* Qw = (float*)d_ws;
    float* Kw = Qw + qkv_elems;
    float* Vw = Kw + qkv_elems;

    const dim3 pg((B * S) / BM, DM / BN);
    proj_kernel<<<pg, 256, 0, stream>>>(hs, Wq, Qw);
    proj_kernel<<<pg, 256, 0, stream>>>(hs, Wk, Kw);
    proj_kernel<<<pg, 256, 0, stream>>>(hs, Wv, Vw);

    rope_kernel<<<(B * H * S * 32) / 256, 256, 0, stream>>>(Qw, Kw, pos);

    attn_kernel<<<dim3(S / 256, B * H), 256, 0, stream>>>(Qw, Kw, Vw, mask, out);
}

// Round 2
// 657.767 us; speedup vs baseline: 3.9328x; 3.9328x over previous
//
#include <hip/hip_runtime.h>
#include <math.h>

// Problem constants (from reference)
#define B  2
#define S  2048
#define DM 1024
#define H  16
#define Dh 64
#define BH (B*H)

typedef short  bf16x8 __attribute__((ext_vector_type(8)));
typedef float  f32x4  __attribute__((ext_vector_type(4)));

__device__ __forceinline__ unsigned short f2bf(float f) {
    unsigned u = __float_as_uint(f);
    u = (u + 0x7fffu + ((u >> 16) & 1u)) >> 16;   // RNE, no NaN inputs here
    return (unsigned short)u;
}
__device__ __forceinline__ float bf2f(unsigned short h) {
    return __uint_as_float((unsigned)h << 16);
}

// ---------------------------------------------------------------------------
// Kernel 1: projection GEMM.  C = X @ W^T  (fp32 math, bf16 output)
//   X: (B*S, DM) fp32, W: (DM, DM) fp32 (rows = out dim)
//   out: [B, H, S, Dh] bf16
// ---------------------------------------------------------------------------
#define BM 64
#define BN 64
#define BK 16

__global__ __launch_bounds__(256) void proj_kernel(const float* __restrict__ X,
                                                   const float* __restrict__ W,
                                                   unsigned short* __restrict__ out) {
    __shared__ __align__(16) float As[BK][BM];
    __shared__ __align__(16) float Bs[BK][BN];

    const int t  = threadIdx.x;
    const int tx = t & 15;        // n direction
    const int ty = t >> 4;        // m direction
    const int m0 = blockIdx.x * BM;
    const int n0 = blockIdx.y * BN;

    const int arow = t >> 2;            // 0..63
    const int acol = (t & 3) * 4;       // 0,4,8,12

    float acc[4][4] = {};

    for (int k0 = 0; k0 < DM; k0 += BK) {
        const float4 a = *(const float4*)(X + (size_t)(m0 + arow) * DM + k0 + acol);
        const float4 w = *(const float4*)(W + (size_t)(n0 + arow) * DM + k0 + acol);
        __syncthreads();
        As[acol + 0][arow] = a.x; As[acol + 1][arow] = a.y;
        As[acol + 2][arow] = a.z; As[acol + 3][arow] = a.w;
        Bs[acol + 0][arow] = w.x; Bs[acol + 1][arow] = w.y;
        Bs[acol + 2][arow] = w.z; Bs[acol + 3][arow] = w.w;
        __syncthreads();

        #pragma unroll
        for (int kk = 0; kk < BK; ++kk) {
            const float4 a4 = *(const float4*)&As[kk][ty * 4];
            const float4 b4 = *(const float4*)&Bs[kk][tx * 4];
            const float av[4] = {a4.x, a4.y, a4.z, a4.w};
            const float bv[4] = {b4.x, b4.y, b4.z, b4.w};
            #pragma unroll
            for (int i = 0; i < 4; ++i)
                #pragma unroll
                for (int j = 0; j < 4; ++j)
                    acc[i][j] += av[i] * bv[j];
        }
    }

    const int hh = n0 >> 6;               // BN == Dh: one head per n-tile
    #pragma unroll
    for (int i = 0; i < 4; ++i) {
        const int m  = m0 + ty * 4 + i;
        const int bb = m >> 11;           // m / S
        const int ss = m & (S - 1);
        ushort4 ov;
        ov.x = f2bf(acc[i][0]); ov.y = f2bf(acc[i][1]);
        ov.z = f2bf(acc[i][2]); ov.w = f2bf(acc[i][3]);
        *(ushort4*)(out + ((size_t)(bb * H + hh) * S + ss) * Dh + tx * 4) = ov;
    }
}

// ---------------------------------------------------------------------------
// Kernel 2: RoPE (+ q scale), in place on bf16 Q and K (fp32 math).
// ---------------------------------------------------------------------------
__global__ __launch_bounds__(256) void rope_kernel(unsigned short* __restrict__ Q,
                                                   unsigned short* __restrict__ K,
                                                   const int* __restrict__ pos) {
    const int idx = blockIdx.x * 256 + threadIdx.x;   // < B*H*S*32 = 2^21
    const int i = idx & 31;
    const int s = (idx >> 5) & (S - 1);
    const int h = (idx >> 16) & (H - 1);
    const int b = idx >> 20;

    const float p   = (float)pos[b * S + s];
    const float inv = powf(10000.0f, -(float)(2 * i) * (1.0f / 64.0f));
    float sn, cs;
    sincosf(p * inv, &sn, &cs);

    const size_t base = ((size_t)(b * H + h) * S + s) * Dh;
    const float q0 = bf2f(Q[base + i]), q1 = bf2f(Q[base + i + 32]);
    Q[base + i]      = f2bf((q0 * cs - q1 * sn) * 0.125f);   // D^-0.5
    Q[base + i + 32] = f2bf((q1 * cs + q0 * sn) * 0.125f);
    const float k0 = bf2f(K[base + i]), k1 = bf2f(K[base + i + 32]);
    K[base + i]      = f2bf(k0 * cs - k1 * sn);
    K[base + i + 32] = f2bf(k1 * cs + k0 * sn);
}

// ---------------------------------------------------------------------------
// Kernel 3: flash attention, bf16 MFMA (16x16x32), fp32 softmax state.
//   grid = (S/64, B*H), block = 256 (4 waves). Wave w owns q rows
//   [blk*64 + w*16, +16). K tile [key][d] and V tile transposed [d][key]
//   staged in LDS (stride 72 bf16 to spread banks); mask tile staged fp32.
//   P round-trips through LDS (C-layout -> A-layout per m120).
// ---------------------------------------------------------------------------
#define KT 64          // keys per tile
#define KS 72          // padded bf16 row stride (144 B: 16B-aligned, 4-bank rotate)
#define MSS 68         // padded mask row stride (fp32)

__global__ __launch_bounds__(256) void attn_kernel(const unsigned short* __restrict__ Q,
                                                   const unsigned short* __restrict__ K,
                                                   const unsigned short* __restrict__ V,
                                                   const float* __restrict__ mask,
                                                   float* __restrict__ out) {
    __shared__ __align__(16) unsigned short Ks[KT * KS];      // [key][d]
    __shared__ __align__(16) unsigned short Vt[Dh * KS];      // [d][key]
    __shared__ __align__(16) float          Ms[64 * MSS];     // [q][key]
    __shared__ __align__(16) unsigned short Ps[4 * 16 * KS];  // per wave [q][key]

    const int tid  = threadIdx.x;
    const int w    = tid >> 6;
    const int lane = tid & 63;
    const int col  = lane & 15;       // MFMA n / A-m index
    const int quad = lane >> 4;
    const int bh   = blockIdx.y;
    const int b    = bh >> 4, h = bh & 15;
    const int q0   = blockIdx.x * 64;     // block's q base

    // Q A-fragments (row = col, k = quad*8+j), held in registers for all tiles
    const unsigned short* qrow = Q + ((size_t)bh * S + (q0 + w * 16 + col)) * Dh;
    const bf16x8 qa0 = *(const bf16x8*)(qrow + quad * 8);
    const bf16x8 qa1 = *(const bf16x8*)(qrow + 32 + quad * 8);

    f32x4 o[4] = {};
    float m_i[4] = {-INFINITY, -INFINITY, -INFINITY, -INFINITY};
    float l_i[4] = {0.f, 0.f, 0.f, 0.f};

    for (int kt = 0; kt < S / KT; ++kt) {
        __syncthreads();   // previous tile's LDS reads done
        // ---- stage K tile and transposed V tile ----
        #pragma unroll
        for (int c = 0; c < 2; ++c) {
            const int idx = tid + c * 256;           // 0..511
            const int row = idx >> 3;                // key 0..63
            const int c8  = (idx & 7) * 8;           // d chunk
            const size_t g = ((size_t)bh * S + kt * KT + row) * Dh + c8;
            *(bf16x8*)&Ks[row * KS + c8] = *(const bf16x8*)(K + g);
            const bf16x8 vv = *(const bf16x8*)(V + g);
            #pragma unroll
            for (int j = 0; j < 8; ++j)
                Vt[(c8 + j) * KS + row] = ((const unsigned short*)&vv)[j];
        }
        // ---- stage mask tile (fp32, coalesced) ----
        #pragma unroll
        for (int c = 0; c < 4; ++c) {
            const int idx = tid + c * 256;           // float4 chunk 0..1023
            const int row = idx >> 4;
            const int c4  = (idx & 15) * 4;
            const float4 mv = *(const float4*)(mask + ((size_t)b * S + q0 + row) * S + kt * KT + c4);
            *(float4*)&Ms[row * MSS + c4] = mv;
        }
        __syncthreads();

        // ---- scores: S = Q @ K^T  (4 frags of 16q x 16k) ----
        f32x4 sc[4];
        #pragma unroll
        for (int f = 0; f < 4; ++f) {
            const bf16x8 kb0 = *(const bf16x8*)&Ks[(f * 16 + col) * KS + quad * 8];
            const bf16x8 kb1 = *(const bf16x8*)&Ks[(f * 16 + col) * KS + 32 + quad * 8];
            f32x4 c = {};
            c = __builtin_amdgcn_mfma_f32_16x16x32_bf16(qa0, kb0, c, 0, 0, 0);
            c = __builtin_amdgcn_mfma_f32_16x16x32_bf16(qa1, kb1, c, 0, 0, 0);
            sc[f] = c;
        }

        // ---- mask add + online softmax (rows quad*4+r, cols f*16+col) ----
        #pragma unroll
        for (int r = 0; r < 4; ++r) {
            const int mrow = (w * 16 + quad * 4 + r) * MSS;
            #pragma unroll
            for (int f = 0; f < 4; ++f)
                sc[f][r] += Ms[mrow + f * 16 + col];

            float t = fmaxf(fmaxf(sc[0][r], sc[1][r]), fmaxf(sc[2][r], sc[3][r]));
            t = fmaxf(t, __shfl_xor(t, 1, 64));
            t = fmaxf(t, __shfl_xor(t, 2, 64));
            t = fmaxf(t, __shfl_xor(t, 4, 64));
            t = fmaxf(t, __shfl_xor(t, 8, 64));

            const float mnew = fmaxf(m_i[r], t);
            const float corr = __expf(m_i[r] - mnew);   // exp(-inf)=0 first tile
            m_i[r] = mnew;
            float rs = 0.f;
            #pragma unroll
            for (int f = 0; f < 4; ++f) {
                const float pv = __expf(sc[f][r] - mnew);
                sc[f][r] = pv;
                rs += pv;
            }
            rs += __shfl_xor(rs, 1, 64);
            rs += __shfl_xor(rs, 2, 64);
            rs += __shfl_xor(rs, 4, 64);
            rs += __shfl_xor(rs, 8, 64);
            l_i[r] = l_i[r] * corr + rs;
            #pragma unroll
            for (int g = 0; g < 4; ++g) o[g][r] *= corr;
        }

        // ---- P: C-layout -> LDS -> A-layout (per-wave region) ----
        unsigned short* pw = &Ps[w * 16 * KS];
        #pragma unroll
        for (int r = 0; r < 4; ++r)
            #pragma unroll
            for (int f = 0; f < 4; ++f)
                pw[(quad * 4 + r) * KS + f * 16 + col] = f2bf(sc[f][r]);
        __syncthreads();   // guarantees wave's ds_writes visible before reads

        // ---- O += P @ V ----
        #pragma unroll
        for (int kc = 0; kc < 2; ++kc) {
            const bf16x8 pa = *(const bf16x8*)&pw[col * KS + kc * 32 + quad * 8];
            #pragma unroll
            for (int g = 0; g < 4; ++g) {
                const bf16x8 vb = *(const bf16x8*)&Vt[(g * 16 + col) * KS + kc * 32 + quad * 8];
                o[g] = __builtin_amdgcn_mfma_f32_16x16x32_bf16(pa, vb, o[g], 0, 0, 0);
            }
        }
    }

    // ---- epilogue: normalize, write ctx[b, s, h*64+d] (fp32) ----
    #pragma unroll
    for (int r = 0; r < 4; ++r) {
        const float inv = 1.f / l_i[r];
        const int   qa  = q0 + w * 16 + quad * 4 + r;
        float* op = out + ((size_t)b * S + qa) * DM + h * Dh;
        #pragma unroll
        for (int g = 0; g < 4; ++g)
            op[g * 16 + col] = o[g][r] * inv;
    }
}

// ---------------------------------------------------------------------------
extern "C" void kernel_launch(void* const* d_in, const int* in_sizes, int n_in,
                              void* d_out, int out_size, void* d_ws, size_t ws_size,
                              hipStream_t stream) {
    const float* hs   = (const float*)d_in[0];  // (B,S,DM)
    const float* mask = (const float*)d_in[1];  // (B,1,S,S)
    const int*   pos  = (const int*)  d_in[2];  // (B,S)
    const float* Wq   = (const float*)d_in[3];
    const float* Wk   = (const float*)d_in[4];
    const float* Wv   = (const float*)d_in[5];
    float* out = (float*)d_out;

    // workspace: bf16 Q, K, V each B*H*S*Dh (8.4 MB each)
    const size_t qkv_elems = (size_t)B * H * S * Dh;
    unsigned short* Qb = (unsigned short*)d_ws;
    unsigned short* Kb = Qb + qkv_elems;
    unsigned short* Vb = Kb + qkv_elems;

    const dim3 pg((B * S) / BM, DM / BN);
    proj_kernel<<<pg, 256, 0, stream>>>(hs, Wq, Qb);
    proj_kernel<<<pg, 256, 0, stream>>>(hs, Wk, Kb);
    proj_kernel<<<pg, 256, 0, stream>>>(hs, Wv, Vb);

    rope_kernel<<<(B * H * S * 32) / 256, 256, 0, stream>>>(Qb, Kb, pos);

    attn_kernel<<<dim3(S / 64, BH), 256, 0, stream>>>(Qb, Kb, Vb, mask, out);
}

// Round 6
// 247.810 us; speedup vs baseline: 10.4389x; 2.6543x over previous
//
#include <hip/hip_runtime.h>
#include <math.h>

// Problem constants (from reference)
#define B  2
#define S  2048
#define DM 1024
#define H  16
#define Dh 64
#define BH (B*H)

typedef short  bf16x8 __attribute__((ext_vector_type(8)));
typedef float  f32x4  __attribute__((ext_vector_type(4)));

__device__ __forceinline__ unsigned short f2bf(float f) {
    unsigned u = __float_as_uint(f);
    u = (u + 0x7fffu + ((u >> 16) & 1u)) >> 16;   // RNE, no NaN inputs here
    return (unsigned short)u;
}
__device__ __forceinline__ float bf2f(unsigned short h) {
    return __uint_as_float((unsigned)h << 16);
}

// ---------------------------------------------------------------------------
// Kernel 0: cast hidden_states + Wq|Wk|Wv (fp32) to bf16 workspace buffers.
//   Xb: 4194304 elems;  Wb: [3][1024][1024] contiguous (3145728 elems).
// ---------------------------------------------------------------------------
__global__ __launch_bounds__(256) void cast_kernel(const float* __restrict__ X,
                                                   const float* __restrict__ Wq,
                                                   const float* __restrict__ Wk,
                                                   const float* __restrict__ Wv,
                                                   unsigned short* __restrict__ Xb,
                                                   unsigned short* __restrict__ Wb) {
    const long c = (long)(blockIdx.x * 256 + threadIdx.x) * 4;
    const float* src;
    unsigned short* dst;
    if (c < 4194304L) {
        src = X + c;  dst = Xb + c;
    } else {
        const long c2 = c - 4194304L;
        const int  wi = (int)(c2 >> 20);
        const long r  = c2 & 1048575L;
        src = (wi == 0 ? Wq : (wi == 1 ? Wk : Wv)) + r;
        dst = Wb + c2;
    }
    const float4 v = *(const float4*)src;
    ushort4 o;
    o.x = f2bf(v.x); o.y = f2bf(v.y); o.z = f2bf(v.z); o.w = f2bf(v.w);
    *(ushort4*)dst = o;
}

// ---------------------------------------------------------------------------
// Kernel 1: fused QKV GEMM, bf16 MFMA.  C[m][n] = sum_k Xb[m][k]*Wb[n][k]
//   M=4096 (b,s), N=3072 (w,h,d), K=1024. 128x128 tile, BK=32, 4 waves,
//   each wave 64x64 via 4x4 frags of 16x16x32. Epilogue scatters into
//   Qb/Kb/Vb [B,H,S,Dh] bf16.
// ---------------------------------------------------------------------------
__global__ __launch_bounds__(256) void qkv_gemm(const unsigned short* __restrict__ Xb,
                                                const unsigned short* __restrict__ Wb,
                                                unsigned short* __restrict__ Qb,
                                                unsigned short* __restrict__ Kb,
                                                unsigned short* __restrict__ Vb) {
    __shared__ __align__(16) unsigned short As[128 * 32];
    __shared__ __align__(16) unsigned short Bs[128 * 32];

    const int tid  = threadIdx.x;
    const int w    = tid >> 6;
    const int lane = tid & 63;
    const int col  = lane & 15;
    const int quad = lane >> 4;
    const int m0 = blockIdx.x * 128;
    const int n0 = blockIdx.y * 128;
    const int mw = (w & 1) * 64;
    const int nw = (w >> 1) * 64;

    f32x4 acc[4][4] = {};

    for (int k0 = 0; k0 < 1024; k0 += 32) {
        __syncthreads();
        #pragma unroll
        for (int i = 0; i < 2; ++i) {
            const int c   = tid + i * 256;       // 16B chunk id, 0..511
            const int row = c >> 2;
            const int k8  = (c & 3) * 8;
            *(bf16x8*)&As[c * 8] = *(const bf16x8*)(Xb + (size_t)(m0 + row) * 1024 + k0 + k8);
            *(bf16x8*)&Bs[c * 8] = *(const bf16x8*)(Wb + (size_t)(n0 + row) * 1024 + k0 + k8);
        }
        __syncthreads();

        bf16x8 a[4], bf[4];
        #pragma unroll
        for (int i = 0; i < 4; ++i)
            a[i] = *(const bf16x8*)&As[(mw + i * 16 + col) * 32 + quad * 8];
        #pragma unroll
        for (int j = 0; j < 4; ++j)
            bf[j] = *(const bf16x8*)&Bs[(nw + j * 16 + col) * 32 + quad * 8];
        #pragma unroll
        for (int i = 0; i < 4; ++i)
            #pragma unroll
            for (int j = 0; j < 4; ++j)
                acc[i][j] = __builtin_amdgcn_mfma_f32_16x16x32_bf16(a[i], bf[j], acc[i][j], 0, 0, 0);
    }

    // epilogue: C row = m0+mw+i*16+quad*4+r, col = n0+nw+j*16+col
    const int wsel = n0 >> 10;                 // whole 128-tile inside one weight
    unsigned short* dp = (wsel == 0) ? Qb : ((wsel == 1) ? Kb : Vb);
    #pragma unroll
    for (int i = 0; i < 4; ++i)
        #pragma unroll
        for (int j = 0; j < 4; ++j)
            #pragma unroll
            for (int r = 0; r < 4; ++r) {
                const int m  = m0 + mw + i * 16 + quad * 4 + r;
                const int n  = n0 + nw + j * 16 + col;
                const int n1 = n & 1023;
                const int hh = n1 >> 6, d = n1 & 63;
                const int bb = m >> 11, ss = m & 2047;
                dp[((size_t)(bb * H + hh) * S + ss) * Dh + d] = f2bf(acc[i][j][r]);
            }
}

// ---------------------------------------------------------------------------
// Kernel 2: RoPE (+ q scale), in place on bf16 Q and K (fp32 math).
// ---------------------------------------------------------------------------
__global__ __launch_bounds__(256) void rope_kernel(unsigned short* __restrict__ Q,
                                                   unsigned short* __restrict__ K,
                                                   const int* __restrict__ pos) {
    const int idx = blockIdx.x * 256 + threadIdx.x;   // < B*H*S*32 = 2^21
    const int i = idx & 31;
    const int s = (idx >> 5) & (S - 1);
    const int h = (idx >> 16) & (H - 1);
    const int b = idx >> 20;

    const float p   = (float)pos[b * S + s];
    const float inv = exp2f(-(float)i * 0.41524101186092029f);  // log2(1e4)/32
    float sn, cs;
    sincosf(p * inv, &sn, &cs);

    const size_t base = ((size_t)(b * H + h) * S + s) * Dh;
    const float q0 = bf2f(Q[base + i]), q1 = bf2f(Q[base + i + 32]);
    Q[base + i]      = f2bf((q0 * cs - q1 * sn) * 0.125f);   // D^-0.5
    Q[base + i + 32] = f2bf((q1 * cs + q0 * sn) * 0.125f);
    const float k0 = bf2f(K[base + i]), k1 = bf2f(K[base + i + 32]);
    K[base + i]      = f2bf(k0 * cs - k1 * sn);
    K[base + i + 32] = f2bf(k1 * cs + k0 * sn);
}

// ---------------------------------------------------------------------------
// Kernel 3: flash attention, transposed-score form.
//   S^T = K·Q^T (A=K, B=Q), softmax along rows/quads, O^T = V^T·P̃ (A=Vt, B=P̃).
//   grid = (S/128, B*H), block = 256 (4 waves); wave owns 32 q rows (2 u-grps).
//   Ks [key][d] stride 72; Vt [d][key^sw] stride 72 (XOR swizzle kills the
//   8-way store conflicts); P̃ per-wave [q][key] stride 72, b32 pair stores.
//   Mask loaded straight from global in C-layout float4s.
// ---------------------------------------------------------------------------
#define KSd 72

__global__ __launch_bounds__(256) void attn_kernel(const unsigned short* __restrict__ Q,
                                                   const unsigned short* __restrict__ K,
                                                   const unsigned short* __restrict__ V,
                                                   const float* __restrict__ mask,
                                                   float* __restrict__ out) {
    __shared__ __align__(16) unsigned short Ks[64 * KSd];
    __shared__ __align__(16) unsigned short Vt[64 * KSd];
    __shared__ __align__(16) unsigned short Ps[4 * 32 * KSd];

    const int tid  = threadIdx.x;
    const int w    = tid >> 6;
    const int lane = tid & 63;
    const int col  = lane & 15;
    const int quad = lane >> 4;
    const int bh   = blockIdx.y;
    const int b    = bh >> 4, h = bh & 15;
    const int q0   = blockIdx.x * 128;
    const int qw   = q0 + w * 32;             // wave's q base (32 rows)

    // Q fragments: qa[u][kc] — lane holds Q[q=qw+u*16+col][kc*32+quad*8 ..+7]
    bf16x8 qa[2][2];
    #pragma unroll
    for (int u = 0; u < 2; ++u) {
        const unsigned short* qrow = Q + ((size_t)bh * S + qw + u * 16 + col) * Dh;
        qa[u][0] = *(const bf16x8*)(qrow + quad * 8);
        qa[u][1] = *(const bf16x8*)(qrow + 32 + quad * 8);
    }

    f32x4 o[4][2] = {};                        // O^T frags: [d-frag g][q-frag u]
    float m_i[2] = {-INFINITY, -INFINITY};
    float l_i[2] = {0.f, 0.f};
    const float* mbase = mask + (size_t)b * S * S;
    unsigned short* pw = Ps + w * 32 * KSd;

    for (int kt = 0; kt < S / 64; ++kt) {
        __syncthreads();                       // all waves done with Ks/Vt
        // ---- stage K [key][d] and swizzled V^T [d][key^sw] ----
        #pragma unroll
        for (int cc = 0; cc < 2; ++cc) {
            const int c   = tid + cc * 256;    // 0..511
            const int row = c >> 3;            // key 0..63
            const int c8  = (c & 7) * 8;       // d chunk
            const size_t g = ((size_t)bh * S + kt * 64 + row) * Dh + c8;
            *(bf16x8*)&Ks[row * KSd + c8] = *(const bf16x8*)(K + g);
            const bf16x8 vv = *(const bf16x8*)(V + g);
            #pragma unroll
            for (int j = 0; j < 8; ++j) {
                const int d  = c8 + j;
                const int kk = row ^ (((d >> 3) & 7) << 3);
                Vt[d * KSd + kk] = ((const unsigned short*)&vv)[j];
            }
        }
        __syncthreads();

        // ---- mask prefetch (C-layout: key = kt*64+f*16+quad*4+r, q = col) ----
        float4 mv[4][2];
        #pragma unroll
        for (int u = 0; u < 2; ++u)
            #pragma unroll
            for (int f = 0; f < 4; ++f)
                mv[f][u] = *(const float4*)(mbase + (size_t)(qw + u * 16 + col) * S
                                            + kt * 64 + f * 16 + quad * 4);

        // ---- S^T = K · Q^T : C[m=key][n=q] ----
        f32x4 sc[4][2] = {};
        #pragma unroll
        for (int f = 0; f < 4; ++f) {
            const bf16x8 ka0 = *(const bf16x8*)&Ks[(f * 16 + col) * KSd + quad * 8];
            const bf16x8 ka1 = *(const bf16x8*)&Ks[(f * 16 + col) * KSd + 32 + quad * 8];
            #pragma unroll
            for (int u = 0; u < 2; ++u) {
                sc[f][u] = __builtin_amdgcn_mfma_f32_16x16x32_bf16(ka0, qa[u][0], sc[f][u], 0, 0, 0);
                sc[f][u] = __builtin_amdgcn_mfma_f32_16x16x32_bf16(ka1, qa[u][1], sc[f][u], 0, 0, 0);
            }
        }

        // ---- online softmax per q (= col within u-group) ----
        #pragma unroll
        for (int u = 0; u < 2; ++u) {
            #pragma unroll
            for (int f = 0; f < 4; ++f) {
                sc[f][u][0] += mv[f][u].x; sc[f][u][1] += mv[f][u].y;
                sc[f][u][2] += mv[f][u].z; sc[f][u][3] += mv[f][u].w;
            }
            float t = -INFINITY;
            #pragma unroll
            for (int f = 0; f < 4; ++f)
                #pragma unroll
                for (int r = 0; r < 4; ++r) t = fmaxf(t, sc[f][u][r]);
            t = fmaxf(t, __shfl_xor(t, 16, 64));
            t = fmaxf(t, __shfl_xor(t, 32, 64));

            const float mnew = fmaxf(m_i[u], t);
            const float corr = __expf(m_i[u] - mnew);   // 0 on first tile
            m_i[u] = mnew;
            float rs = 0.f;
            #pragma unroll
            for (int f = 0; f < 4; ++f)
                #pragma unroll
                for (int r = 0; r < 4; ++r) {
                    const float pv = __expf(sc[f][u][r] - mnew);
                    sc[f][u][r] = pv;
                    rs += pv;
                }
            rs += __shfl_xor(rs, 16, 64);
            rs += __shfl_xor(rs, 32, 64);
            l_i[u] = l_i[u] * corr + rs;
            #pragma unroll
            for (int g = 0; g < 4; ++g) {
                o[g][u][0] *= corr; o[g][u][1] *= corr;
                o[g][u][2] *= corr; o[g][u][3] *= corr;
            }
            // ---- store P̃ [q][key] as packed b32 pairs ----
            unsigned short* pq = pw + (u * 16 + col) * KSd;
            #pragma unroll
            for (int f = 0; f < 4; ++f) {
                const unsigned v0 = (unsigned)f2bf(sc[f][u][0]) | ((unsigned)f2bf(sc[f][u][1]) << 16);
                const unsigned v1 = (unsigned)f2bf(sc[f][u][2]) | ((unsigned)f2bf(sc[f][u][3]) << 16);
                *(unsigned*)&pq[f * 16 + quad * 4]     = v0;
                *(unsigned*)&pq[f * 16 + quad * 4 + 2] = v1;
            }
        }
        __threadfence_block();   // wave-private Ps: lgkmcnt drain, no barrier

        // ---- O^T += V^T · P̃ ----
        #pragma unroll
        for (int kc = 0; kc < 2; ++kc) {
            bf16x8 pb[2];
            #pragma unroll
            for (int u = 0; u < 2; ++u)
                pb[u] = *(const bf16x8*)&pw[(u * 16 + col) * KSd + kc * 32 + quad * 8];
            #pragma unroll
            for (int g = 0; g < 4; ++g) {
                const int d  = g * 16 + col;
                const int sw = (((d >> 3) & 7) << 3);
                const bf16x8 va = *(const bf16x8*)&Vt[d * KSd + ((kc * 32 + quad * 8) ^ sw)];
                #pragma unroll
                for (int u = 0; u < 2; ++u)
                    o[g][u] = __builtin_amdgcn_mfma_f32_16x16x32_bf16(va, pb[u], o[g][u], 0, 0, 0);
            }
        }
    }

    // ---- epilogue: O^T lane (quad,r,col) holds O[q=qw+u*16+col][d=g*16+quad*4+r]
    #pragma unroll
    for (int u = 0; u < 2; ++u) {
        const float inv = 1.f / l_i[u];
        const int   qg  = qw + u * 16 + col;
        float* op = out + ((size_t)b * S + qg) * DM + h * Dh + quad * 4;
        #pragma unroll
        for (int g = 0; g < 4; ++g) {
            float4 ov;
            ov.x = o[g][u][0] * inv; ov.y = o[g][u][1] * inv;
            ov.z = o[g][u][2] * inv; ov.w = o[g][u][3] * inv;
            *(float4*)(op + g * 16) = ov;
        }
    }
}

// ---------------------------------------------------------------------------
extern "C" void kernel_launch(void* const* d_in, const int* in_sizes, int n_in,
                              void* d_out, int out_size, void* d_ws, size_t ws_size,
                              hipStream_t stream) {
    const float* hs   = (const float*)d_in[0];  // (B,S,DM)
    const float* mask = (const float*)d_in[1];  // (B,1,S,S)
    const int*   pos  = (const int*)  d_in[2];  // (B,S)
    const float* Wq   = (const float*)d_in[3];
    const float* Wk   = (const float*)d_in[4];
    const float* Wv   = (const float*)d_in[5];
    float* out = (float*)d_out;

    // workspace layout (bf16 elems):
    //   Xb 4,194,304 | Wb 3,145,728 | Qb,Kb,Vb each B*H*S*Dh = 4,194,304
    // ROUND-3/4/5 BUG WAS HERE: offsets used 2,097,152 (dropped B=2), so K
    // aliased Q's b=1 half and V aliased K's b=1 half.
    unsigned short* Xb = (unsigned short*)d_ws;
    unsigned short* Wb = Xb + 4194304;
    unsigned short* Qb = Wb + 3145728;
    unsigned short* Kb = Qb + 4194304;
    unsigned short* Vb = Kb + 4194304;

    cast_kernel<<<7168, 256, 0, stream>>>(hs, Wq, Wk, Wv, Xb, Wb);
    qkv_gemm<<<dim3(32, 24), 256, 0, stream>>>(Xb, Wb, Qb, Kb, Vb);
    rope_kernel<<<8192, 256, 0, stream>>>(Qb, Kb, pos);
    attn_kernel<<<dim3(S / 128, BH), 256, 0, stream>>>(Qb, Kb, Vb, mask, out);
}

// Round 7
// 243.052 us; speedup vs baseline: 10.6433x; 1.0196x over previous
//
#include <hip/hip_runtime.h>
#include <math.h>

// Problem constants (from reference)
#define B  2
#define S  2048
#define DM 1024
#define H  16
#define Dh 64
#define BH (B*H)

typedef short  bf16x8 __attribute__((ext_vector_type(8)));
typedef float  f32x4  __attribute__((ext_vector_type(4)));

__device__ __forceinline__ unsigned short f2bf(float f) {
    unsigned u = __float_as_uint(f);
    u = (u + 0x7fffu + ((u >> 16) & 1u)) >> 16;   // RNE, no NaN inputs here
    return (unsigned short)u;
}
__device__ __forceinline__ float bf2f(unsigned short h) {
    return __uint_as_float((unsigned)h << 16);
}

// async global->LDS, 16B per lane: LDS dest = wave-uniform base + lane*16
__device__ __forceinline__ void gload_lds16(const unsigned short* g, unsigned short* l) {
    __builtin_amdgcn_global_load_lds(
        (const __attribute__((address_space(1))) unsigned int*)g,
        (__attribute__((address_space(3))) unsigned int*)l,
        16, 0, 0);
}

// ---------------------------------------------------------------------------
// Kernel 0: cast hidden_states + Wq|Wk|Wv (fp32) to bf16 workspace buffers.
//   Xb: 4194304 elems;  Wb: [3][1024][1024] contiguous (3145728 elems).
// ---------------------------------------------------------------------------
__global__ __launch_bounds__(256) void cast_kernel(const float* __restrict__ X,
                                                   const float* __restrict__ Wq,
                                                   const float* __restrict__ Wk,
                                                   const float* __restrict__ Wv,
                                                   unsigned short* __restrict__ Xb,
                                                   unsigned short* __restrict__ Wb) {
    const long c = (long)(blockIdx.x * 256 + threadIdx.x) * 4;
    const float* src;
    unsigned short* dst;
    if (c < 4194304L) {
        src = X + c;  dst = Xb + c;
    } else {
        const long c2 = c - 4194304L;
        const int  wi = (int)(c2 >> 20);
        const long r  = c2 & 1048575L;
        src = (wi == 0 ? Wq : (wi == 1 ? Wk : Wv)) + r;
        dst = Wb + c2;
    }
    const float4 v = *(const float4*)src;
    ushort4 o;
    o.x = f2bf(v.x); o.y = f2bf(v.y); o.z = f2bf(v.z); o.w = f2bf(v.w);
    *(ushort4*)dst = o;
}

// ---------------------------------------------------------------------------
// Kernel 1: fused QKV GEMM, bf16 MFMA, m97-style global_load_lds staging.
//   C[m][n] = sum_k Xb[m][k]*Wb[n][k];  M=4096, N=3072, K=1024.
//   128x128 tile, BK=32, 4 waves, each wave 64x64 via 4x4 frags of 16x16x32.
//   Epilogue scatters into Qb/Kb/Vb [B,H,S,Dh] bf16.
// ---------------------------------------------------------------------------
__global__ __launch_bounds__(256) void qkv_gemm(const unsigned short* __restrict__ Xb,
                                                const unsigned short* __restrict__ Wb,
                                                unsigned short* __restrict__ Qb,
                                                unsigned short* __restrict__ Kb,
                                                unsigned short* __restrict__ Vb) {
    __shared__ __align__(16) unsigned short As[128 * 32];
    __shared__ __align__(16) unsigned short Bs[128 * 32];

    const int tid  = threadIdx.x;
    const int w    = tid >> 6;
    const int lane = tid & 63;
    const int col  = lane & 15;
    const int quad = lane >> 4;
    const int m0 = blockIdx.x * 128;
    const int n0 = blockIdx.y * 128;
    const int mw = (w & 1) * 64;
    const int nw = (w >> 1) * 64;

    // staging geometry: wave covers 16 rows per issue (64 lanes x 16B = 1KB),
    // lane i -> row = i>>2, k8 = (i&3)*8 within the wave's 16-row slab.
    const int srow = (lane >> 2);
    const int sk8  = (lane & 3) * 8;

    f32x4 acc[4][4] = {};

    for (int k0 = 0; k0 < 1024; k0 += 32) {
        __syncthreads();
        #pragma unroll
        for (int it = 0; it < 2; ++it) {
            const int rbase = w * 16 + it * 64;       // wave's slab base row
            gload_lds16(Xb + (size_t)(m0 + rbase + srow) * 1024 + k0 + sk8,
                        &As[rbase * 32]);
            gload_lds16(Wb + (size_t)(n0 + rbase + srow) * 1024 + k0 + sk8,
                        &Bs[rbase * 32]);
        }
        __syncthreads();   // drains vmcnt (global_load_lds) before use

        bf16x8 a[4], bb[4];
        #pragma unroll
        for (int i = 0; i < 4; ++i)
            a[i] = *(const bf16x8*)&As[(mw + i * 16 + col) * 32 + quad * 8];
        #pragma unroll
        for (int j = 0; j < 4; ++j)
            bb[j] = *(const bf16x8*)&Bs[(nw + j * 16 + col) * 32 + quad * 8];
        #pragma unroll
        for (int i = 0; i < 4; ++i)
            #pragma unroll
            for (int j = 0; j < 4; ++j)
                acc[i][j] = __builtin_amdgcn_mfma_f32_16x16x32_bf16(a[i], bb[j], acc[i][j], 0, 0, 0);
    }

    // epilogue: C row = m0+mw+i*16+quad*4+r, col = n0+nw+j*16+col
    const int wsel = n0 >> 10;                 // whole 128-tile inside one weight
    unsigned short* dp = (wsel == 0) ? Qb : ((wsel == 1) ? Kb : Vb);
    #pragma unroll
    for (int i = 0; i < 4; ++i)
        #pragma unroll
        for (int j = 0; j < 4; ++j)
            #pragma unroll
            for (int r = 0; r < 4; ++r) {
                const int m  = m0 + mw + i * 16 + quad * 4 + r;
                const int n  = n0 + nw + j * 16 + col;
                const int n1 = n & 1023;
                const int hh = n1 >> 6, d = n1 & 63;
                const int bb2 = m >> 11, ss = m & 2047;
                dp[((size_t)(bb2 * H + hh) * S + ss) * Dh + d] = f2bf(acc[i][j][r]);
            }
}

// ---------------------------------------------------------------------------
// Kernel 2: RoPE (+ q scale), in place on bf16 Q and K (fp32 math).
// ---------------------------------------------------------------------------
__global__ __launch_bounds__(256) void rope_kernel(unsigned short* __restrict__ Q,
                                                   unsigned short* __restrict__ K,
                                                   const int* __restrict__ pos) {
    const int idx = blockIdx.x * 256 + threadIdx.x;   // < B*H*S*32 = 2^21
    const int i = idx & 31;
    const int s = (idx >> 5) & (S - 1);
    const int h = (idx >> 16) & (H - 1);
    const int b = idx >> 20;

    const float p   = (float)pos[b * S + s];
    const float inv = exp2f(-(float)i * 0.41524101186092029f);  // log2(1e4)/32
    float sn, cs;
    sincosf(p * inv, &sn, &cs);

    const size_t base = ((size_t)(b * H + h) * S + s) * Dh;
    const float q0 = bf2f(Q[base + i]), q1 = bf2f(Q[base + i + 32]);
    Q[base + i]      = f2bf((q0 * cs - q1 * sn) * 0.125f);   // D^-0.5
    Q[base + i + 32] = f2bf((q1 * cs + q0 * sn) * 0.125f);
    const float k0 = bf2f(K[base + i]), k1 = bf2f(K[base + i + 32]);
    K[base + i]      = f2bf(k0 * cs - k1 * sn);
    K[base + i + 32] = f2bf(k1 * cs + k0 * sn);
}

// ---------------------------------------------------------------------------
// Kernel 3: flash attention, transposed-score form, 8 waves / 512 threads.
//   S^T = K·Q^T (A=K, B=Q), softmax along rows/quads, O^T = V^T·P̃.
//   grid = (S/128, B*H); wave owns 16 q rows -> 16 waves/CU occupancy.
//   Ks [key][d] stride 72; Vt [d][key^sw] stride 72 (XOR swizzle);
//   P̃ per-wave [q][key] stride 72, b32 pair stores. Mask direct from global.
// ---------------------------------------------------------------------------
#define KSd 72

__global__ __launch_bounds__(512) void attn_kernel(const unsigned short* __restrict__ Q,
                                                   const unsigned short* __restrict__ K,
                                                   const unsigned short* __restrict__ V,
                                                   const float* __restrict__ mask,
                                                   float* __restrict__ out) {
    __shared__ __align__(16) unsigned short Ks[64 * KSd];      //  9216 B
    __shared__ __align__(16) unsigned short Vt[64 * KSd];      //  9216 B
    __shared__ __align__(16) unsigned short Ps[8 * 16 * KSd];  // 18432 B

    const int tid  = threadIdx.x;
    const int w    = tid >> 6;        // 0..7
    const int lane = tid & 63;
    const int col  = lane & 15;
    const int quad = lane >> 4;
    const int bh   = blockIdx.y;
    const int b    = bh >> 4, h = bh & 15;
    const int q0   = blockIdx.x * 128;
    const int qw   = q0 + w * 16;     // wave's q base (16 rows)

    // Q fragments: lane holds Q[q=qw+col][kc*32+quad*8 ..+7]
    const unsigned short* qrow = Q + ((size_t)bh * S + qw + col) * Dh;
    const bf16x8 qa0 = *(const bf16x8*)(qrow + quad * 8);
    const bf16x8 qa1 = *(const bf16x8*)(qrow + 32 + quad * 8);

    f32x4 o[4] = {};                  // O^T frags over d (4 x 16)
    float m_i = -INFINITY, l_i = 0.f;
    const float* mrow = mask + (size_t)b * S * S + (size_t)(qw + col) * S;
    unsigned short* pw = Ps + w * 16 * KSd;

    // staging geometry: 512 threads cover the 64x64 tile in one pass
    const int srow = tid >> 3;            // key 0..63
    const int sc8  = (tid & 7) * 8;       // d chunk

    for (int kt = 0; kt < S / 64; ++kt) {
        __syncthreads();                  // all waves done with Ks/Vt
        {
            const size_t g = ((size_t)bh * S + kt * 64 + srow) * Dh + sc8;
            *(bf16x8*)&Ks[srow * KSd + sc8] = *(const bf16x8*)(K + g);
            const bf16x8 vv = *(const bf16x8*)(V + g);
            #pragma unroll
            for (int j = 0; j < 8; ++j) {
                const int d  = sc8 + j;
                const int kk = srow ^ (((d >> 3) & 7) << 3);
                Vt[d * KSd + kk] = ((const unsigned short*)&vv)[j];
            }
        }
        __syncthreads();

        // ---- mask (C-layout: key = kt*64+f*16+quad*4+r, q = col) ----
        float4 mv[4];
        #pragma unroll
        for (int f = 0; f < 4; ++f)
            mv[f] = *(const float4*)(mrow + kt * 64 + f * 16 + quad * 4);

        // ---- S^T = K · Q^T : C[m=key][n=q] ----
        f32x4 sc[4] = {};
        #pragma unroll
        for (int f = 0; f < 4; ++f) {
            const bf16x8 ka0 = *(const bf16x8*)&Ks[(f * 16 + col) * KSd + quad * 8];
            const bf16x8 ka1 = *(const bf16x8*)&Ks[(f * 16 + col) * KSd + 32 + quad * 8];
            sc[f] = __builtin_amdgcn_mfma_f32_16x16x32_bf16(ka0, qa0, sc[f], 0, 0, 0);
            sc[f] = __builtin_amdgcn_mfma_f32_16x16x32_bf16(ka1, qa1, sc[f], 0, 0, 0);
        }

        // ---- online softmax for q = qw+col (16 scores/lane, keys on quad/r) ----
        #pragma unroll
        for (int f = 0; f < 4; ++f) {
            sc[f][0] += mv[f].x; sc[f][1] += mv[f].y;
            sc[f][2] += mv[f].z; sc[f][3] += mv[f].w;
        }
        float t = -INFINITY;
        #pragma unroll
        for (int f = 0; f < 4; ++f)
            #pragma unroll
            for (int r = 0; r < 4; ++r) t = fmaxf(t, sc[f][r]);
        t = fmaxf(t, __shfl_xor(t, 16, 64));
        t = fmaxf(t, __shfl_xor(t, 32, 64));

        const float mnew = fmaxf(m_i, t);
        const float corr = __expf(m_i - mnew);   // 0 on first tile
        m_i = mnew;
        float rs = 0.f;
        #pragma unroll
        for (int f = 0; f < 4; ++f)
            #pragma unroll
            for (int r = 0; r < 4; ++r) {
                const float pv = __expf(sc[f][r] - mnew);
                sc[f][r] = pv;
                rs += pv;
            }
        rs += __shfl_xor(rs, 16, 64);
        rs += __shfl_xor(rs, 32, 64);
        l_i = l_i * corr + rs;
        #pragma unroll
        for (int g = 0; g < 4; ++g) {
            o[g][0] *= corr; o[g][1] *= corr; o[g][2] *= corr; o[g][3] *= corr;
        }

        // ---- store P̃ [q][key] as packed b32 pairs (wave-private region) ----
        unsigned short* pq = pw + col * KSd;
        #pragma unroll
        for (int f = 0; f < 4; ++f) {
            const unsigned v0 = (unsigned)f2bf(sc[f][0]) | ((unsigned)f2bf(sc[f][1]) << 16);
            const unsigned v1 = (unsigned)f2bf(sc[f][2]) | ((unsigned)f2bf(sc[f][3]) << 16);
            *(unsigned*)&pq[f * 16 + quad * 4]     = v0;
            *(unsigned*)&pq[f * 16 + quad * 4 + 2] = v1;
        }
        __threadfence_block();   // wave-private Ps: lgkmcnt drain, no barrier

        // ---- O^T += V^T · P̃ ----
        #pragma unroll
        for (int kc = 0; kc < 2; ++kc) {
            const bf16x8 pb = *(const bf16x8*)&pw[col * KSd + kc * 32 + quad * 8];
            #pragma unroll
            for (int g = 0; g < 4; ++g) {
                const int d  = g * 16 + col;
                const int sw = (((d >> 3) & 7) << 3);
                const bf16x8 va = *(const bf16x8*)&Vt[d * KSd + ((kc * 32 + quad * 8) ^ sw)];
                o[g] = __builtin_amdgcn_mfma_f32_16x16x32_bf16(va, pb, o[g], 0, 0, 0);
            }
        }
    }

    // ---- epilogue: lane (quad,r,col) holds O[q=qw+col][d=g*16+quad*4+r] ----
    const float inv = 1.f / l_i;
    float* op = out + ((size_t)b * S + qw + col) * DM + h * Dh + quad * 4;
    #pragma unroll
    for (int g = 0; g < 4; ++g) {
        float4 ov;
        ov.x = o[g][0] * inv; ov.y = o[g][1] * inv;
        ov.z = o[g][2] * inv; ov.w = o[g][3] * inv;
        *(float4*)(op + g * 16) = ov;
    }
}

// ---------------------------------------------------------------------------
extern "C" void kernel_launch(void* const* d_in, const int* in_sizes, int n_in,
                              void* d_out, int out_size, void* d_ws, size_t ws_size,
                              hipStream_t stream) {
    const float* hs   = (const float*)d_in[0];  // (B,S,DM)
    const float* mask = (const float*)d_in[1];  // (B,1,S,S)
    const int*   pos  = (const int*)  d_in[2];  // (B,S)
    const float* Wq   = (const float*)d_in[3];
    const float* Wk   = (const float*)d_in[4];
    const float* Wv   = (const float*)d_in[5];
    float* out = (float*)d_out;

    // workspace layout (bf16 elems):
    //   Xb 4,194,304 | Wb 3,145,728 | Qb,Kb,Vb each B*H*S*Dh = 4,194,304
    unsigned short* Xb = (unsigned short*)d_ws;
    unsigned short* Wb = Xb + 4194304;
    unsigned short* Qb = Wb + 3145728;
    unsigned short* Kb = Qb + 4194304;
    unsigned short* Vb = Kb + 4194304;

    cast_kernel<<<7168, 256, 0, stream>>>(hs, Wq, Wk, Wv, Xb, Wb);
    qkv_gemm<<<dim3(32, 24), 256, 0, stream>>>(Xb, Wb, Qb, Kb, Vb);
    rope_kernel<<<8192, 256, 0, stream>>>(Qb, Kb, pos);
    attn_kernel<<<dim3(S / 128, BH), 512, 0, stream>>>(Qb, Kb, Vb, mask, out);
}